// Round 4
// baseline (621.712 us; speedup 1.0000x reference)
//
#include <hip/hip_runtime.h>
#include <hip/hip_bf16.h>
#include <math.h>

typedef unsigned short u16;
typedef unsigned int u32;
typedef __attribute__((ext_vector_type(8))) short short8;
typedef __attribute__((ext_vector_type(8))) u16 ushort8;
typedef __attribute__((ext_vector_type(4))) float f32x4;

#define N_B 4
#define L_S 2048
#define E_D 2048
#define NH 16
#define HD 128
#define WIN 1024
#define QW 3072  // QKV buffer row width: 2048 q | 512 k | 512 v
#define LOG2E 1.4426950408889634f

static __device__ __forceinline__ u16 f32_bf16(float f) {
  u32 u = __builtin_bit_cast(u32, f);
  u = (u + 0x7fffu + ((u >> 16) & 1u)) >> 16;  // RNE
  return (u16)u;
}
static __device__ __forceinline__ float bf16_f32(u16 h) {
  u32 u = ((u32)h) << 16;
  return __builtin_bit_cast(float, u);
}
static __device__ __forceinline__ void gload_lds16(const void* g, void* l) {
  __builtin_amdgcn_global_load_lds((__attribute__((address_space(1))) void*)g,
                                   (__attribute__((address_space(3))) void*)l, 16, 0, 0);
}

// ---------------- fp32 -> bf16 cast (n multiple of 8) ----------------
__global__ void k_cast(const float* __restrict__ src, u16* __restrict__ dst, int n8) {
  int i = blockIdx.x * blockDim.x + threadIdx.x;
  if (i >= n8) return;
  const float4* s = (const float4*)src + (size_t)i * 2;
  float4 a = s[0], b = s[1];
  ushort8 v;
  v[0] = f32_bf16(a.x); v[1] = f32_bf16(a.y); v[2] = f32_bf16(a.z); v[3] = f32_bf16(a.w);
  v[4] = f32_bf16(b.x); v[5] = f32_bf16(b.y); v[6] = f32_bf16(b.z); v[7] = f32_bf16(b.w);
  *((ushort8*)dst + i) = v;
}

// ---------------- RoPE cos/sin table: [L][64] ----------------
__global__ void k_rope_table(float* __restrict__ cs, float* __restrict__ sn) {
  int idx = blockIdx.x * blockDim.x + threadIdx.x;  // 2048*64
  int l = idx >> 6, f = idx & 63;
  float freq = exp2f(-(float)f * (13.287712379549449f / 64.0f));  // 10000^(-2f/128)
  float ang = (float)l * freq;
  cs[idx] = cosf(ang);
  sn[idx] = sinf(ang);
}

// ---------------- interleaved RoPE applied in place to Q and K of QKV ----------------
__global__ void k_rope_apply(u16* __restrict__ QKV, const float* __restrict__ cs,
                             const float* __restrict__ sn) {
  int idx = blockIdx.x * blockDim.x + threadIdx.x;  // 8192*20*64 exactly
  int f = idx & 63;
  int rest = idx >> 6;
  int hh = rest % 20;          // 0..15 q heads, 16..19 kv heads
  int row = rest / 20;         // 0..8191 (= n*L + l)
  int l = row & (L_S - 1);
  int col = (hh < NH) ? (hh * HD + 2 * f) : (E_D + (hh - NH) * HD + 2 * f);
  u32* p = (u32*)(QKV + (size_t)row * QW + col);
  u32 v = *p;
  float xr = bf16_f32((u16)(v & 0xffffu));
  float xi = bf16_f32((u16)(v >> 16));
  float c = cs[l * 64 + f], s = sn[l * 64 + f];
  float orr = xr * c - xi * s;
  float oii = xr * s + xi * c;
  *p = (u32)f32_bf16(orr) | ((u32)f32_bf16(oii) << 16);
}

// ---------------- C = A @ B^T, bf16 in, bf16 or f32 out ----------------
// A: MxK row-major (lda), B: NxK row-major (ldb). 128x128 tile, BK=64, 4 waves.
template <int OUT_F32>
__global__ __launch_bounds__(256) void k_gemm_bt(
    const u16* __restrict__ A, int lda,
    const u16* __restrict__ B, int ldb,
    void* __restrict__ Cp, int ldc, int K) {
  __shared__ __align__(16) u16 As[128 * 64];
  __shared__ __align__(16) u16 Bs[128 * 64];
  const int tid = threadIdx.x;
  const int lane = tid & 63, w = tid >> 6;
  const int lr = lane & 15, lg = lane >> 4;
  const int m0 = blockIdx.x * 128, n0 = blockIdx.y * 128;
  const int wm = (w >> 1) * 64, wn = (w & 1) * 64;
  const int srow = tid >> 3, scol = (tid & 7) * 8;  // staging: 16B per lane
  const f32x4 z4 = {0.f, 0.f, 0.f, 0.f};
  f32x4 acc[4][4];
#pragma unroll
  for (int i = 0; i < 4; ++i)
#pragma unroll
    for (int j = 0; j < 4; ++j) acc[i][j] = z4;
  for (int kt = 0; kt < K; kt += 64) {
#pragma unroll
    for (int rr = 0; rr < 4; ++rr) {
      gload_lds16(A + (size_t)(m0 + rr * 32 + srow) * lda + kt + scol,
                  (char*)As + rr * 4096 + w * 1024);
      gload_lds16(B + (size_t)(n0 + rr * 32 + srow) * ldb + kt + scol,
                  (char*)Bs + rr * 4096 + w * 1024);
    }
    __syncthreads();
#pragma unroll
    for (int kk = 0; kk < 64; kk += 32) {
      short8 af[4], bfr[4];
#pragma unroll
      for (int mi = 0; mi < 4; ++mi)
        af[mi] = *(const short8*)(As + (wm + mi * 16 + lr) * 64 + kk + lg * 8);
#pragma unroll
      for (int ni = 0; ni < 4; ++ni)
        bfr[ni] = *(const short8*)(Bs + (wn + ni * 16 + lr) * 64 + kk + lg * 8);
#pragma unroll
      for (int mi = 0; mi < 4; ++mi)
#pragma unroll
        for (int ni = 0; ni < 4; ++ni)
          acc[mi][ni] =
              __builtin_amdgcn_mfma_f32_16x16x32_bf16(af[mi], bfr[ni], acc[mi][ni], 0, 0, 0);
    }
    __syncthreads();
  }
#pragma unroll
  for (int mi = 0; mi < 4; ++mi)
#pragma unroll
    for (int ni = 0; ni < 4; ++ni)
#pragma unroll
      for (int j = 0; j < 4; ++j) {
        size_t r = (size_t)(m0 + wm + mi * 16 + lg * 4 + j);
        int c = n0 + wn + ni * 16 + lr;
        if (OUT_F32)
          ((float*)Cp)[r * ldc + c] = acc[mi][ni][j];
        else
          ((u16*)Cp)[r * ldc + c] = f32_bf16(acc[mi][ni][j]);
      }
}

// ---------------- sliding-window flash attention ----------------
// Grid (L/64, H, N). 4 waves; wave w owns q-rows [qb*64+w*16, +16). KV tile = 32.
// Writes Z (post-softmax output) into the Q region of QKV (Q is in regs first).
__global__ __launch_bounds__(256) void k_attn(u16* __restrict__ QKV) {
  const int qb = blockIdx.x, h = blockIdx.y, b = blockIdx.z;
  const int tid = threadIdx.x;
  const int lane = tid & 63, w = tid >> 6;
  const int lr = lane & 15, lg = lane >> 4;
  const int kh = h >> 2;
  const int qs = qb * 64 + w * 16;
  __shared__ __align__(16) u16 Klds[32 * 128];   // [kv][d]
  __shared__ __align__(16) u16 Vt[128 * 32];     // [d][kv] (transposed)
  __shared__ __align__(16) u16 Plds[4][16 * 32]; // per-wave P
  const float scale = 0.08838834764831845f;      // 1/sqrt(128)
  const size_t rowQ = (size_t)(b * L_S + qs + lr) * QW + h * HD;
  short8 qf[4];
#pragma unroll
  for (int c = 0; c < 4; ++c) qf[c] = *(const short8*)(QKV + rowQ + c * 32 + lg * 8);
  const f32x4 z4 = {0.f, 0.f, 0.f, 0.f};
  f32x4 o[8];
#pragma unroll
  for (int dt = 0; dt < 8; ++dt) o[dt] = z4;
  float mrow[4], lrow[4];
#pragma unroll
  for (int j = 0; j < 4; ++j) { mrow[j] = -3e38f; lrow[j] = 0.f; }
  int t0 = qb * 64 - (WIN - 1);
  if (t0 < 0) t0 = 0;
  t0 >>= 5;
  const int t1 = (qb * 64 + 63) >> 5;
  const int krow = tid >> 4, kcol = (tid & 15) * 8;
  for (int t = t0; t <= t1; ++t) {
    const int kv0 = t * 32;
    // stage K tile (linear) via async copy
#pragma unroll
    for (int rr = 0; rr < 2; ++rr)
      gload_lds16(QKV + (size_t)(b * L_S + kv0 + rr * 16 + krow) * QW + E_D + kh * HD + kcol,
                  (char*)Klds + rr * 4096 + w * 1024);
    // stage V transposed (reg -> scalar ds_write)
#pragma unroll
    for (int rr = 0; rr < 2; ++rr) {
      int cc = rr * 256 + tid;
      int kvr = cc & 31, db = (cc >> 5) * 8;
      short8 vv =
          *(const short8*)(QKV + (size_t)(b * L_S + kv0 + kvr) * QW + E_D + 512 + kh * HD + db);
#pragma unroll
      for (int e = 0; e < 8; ++e) Vt[(db + e) * 32 + kvr] = (u16)vv[e];
    }
    __syncthreads();
    // S = Q K^T (two 16-col tiles)
    f32x4 s0 = z4, s1 = z4;
#pragma unroll
    for (int c = 0; c < 4; ++c) {
      short8 kf0 = *(const short8*)(Klds + lr * 128 + c * 32 + lg * 8);
      short8 kf1 = *(const short8*)(Klds + (16 + lr) * 128 + c * 32 + lg * 8);
      s0 = __builtin_amdgcn_mfma_f32_16x16x32_bf16(qf[c], kf0, s0, 0, 0, 0);
      s1 = __builtin_amdgcn_mfma_f32_16x16x32_bf16(qf[c], kf1, s1, 0, 0, 0);
    }
    // online softmax (rows = lg*4+j, cols = lr / lr+16)
    float p0[4], p1[4], al[4];
    const int g0 = kv0 + lr, g1 = kv0 + 16 + lr;
#pragma unroll
    for (int j = 0; j < 4; ++j) {
      int gr = qs + lg * 4 + j;
      bool a0 = (g0 <= gr) && (g0 > gr - WIN);
      bool a1 = (g1 <= gr) && (g1 > gr - WIN);
      float v0 = a0 ? s0[j] * scale : -3e38f;
      float v1 = a1 ? s1[j] * scale : -3e38f;
      float pm = fmaxf(v0, v1);
      pm = fmaxf(pm, __shfl_xor(pm, 1));
      pm = fmaxf(pm, __shfl_xor(pm, 2));
      pm = fmaxf(pm, __shfl_xor(pm, 4));
      pm = fmaxf(pm, __shfl_xor(pm, 8));
      float mn = fmaxf(mrow[j], pm);
      float alpha = exp2f((mrow[j] - mn) * LOG2E);
      mrow[j] = mn;
      p0[j] = a0 ? exp2f((v0 - mn) * LOG2E) : 0.f;  // explicit predicate: never exp(0) on masked
      p1[j] = a1 ? exp2f((v1 - mn) * LOG2E) : 0.f;
      float rs = p0[j] + p1[j];
      rs += __shfl_xor(rs, 1);
      rs += __shfl_xor(rs, 2);
      rs += __shfl_xor(rs, 4);
      rs += __shfl_xor(rs, 8);
      lrow[j] = lrow[j] * alpha + rs;
      al[j] = alpha;
    }
#pragma unroll
    for (int dt = 0; dt < 8; ++dt) {
      o[dt][0] *= al[0]; o[dt][1] *= al[1]; o[dt][2] *= al[2]; o[dt][3] *= al[3];
    }
    // P -> LDS (C-layout -> A-layout transpose via LDS)
    u16* Pw = &Plds[w][0];
#pragma unroll
    for (int j = 0; j < 4; ++j) {
      Pw[(lg * 4 + j) * 32 + lr] = f32_bf16(p0[j]);
      Pw[(lg * 4 + j) * 32 + 16 + lr] = f32_bf16(p1[j]);
    }
    __syncthreads();
    short8 pf = *(const short8*)(Pw + lr * 32 + lg * 8);
#pragma unroll
    for (int dt = 0; dt < 8; ++dt) {
      short8 vf = *(const short8*)(Vt + (dt * 16 + lr) * 32 + lg * 8);
      o[dt] = __builtin_amdgcn_mfma_f32_16x16x32_bf16(pf, vf, o[dt], 0, 0, 0);
    }
    __syncthreads();
  }
  float inv[4];
#pragma unroll
  for (int j = 0; j < 4; ++j) inv[j] = 1.0f / lrow[j];
#pragma unroll
  for (int dt = 0; dt < 8; ++dt)
#pragma unroll
    for (int j = 0; j < 4; ++j) {
      size_t addr = (size_t)(b * L_S + qs + lg * 4 + j) * QW + h * HD + dt * 16 + lr;
      QKV[addr] = f32_bf16(o[dt][j] * inv[j]);
    }
}

extern "C" void kernel_launch(void* const* d_in, const int* in_sizes, int n_in,
                              void* d_out, int out_size, void* d_ws, size_t ws_size,
                              hipStream_t stream) {
  const float* x  = (const float*)d_in[0];
  const float* Wq = (const float*)d_in[1];
  const float* Wk = (const float*)d_in[2];
  const float* Wv = (const float*)d_in[3];
  const float* Wo = (const float*)d_in[4];
  char* ws = (char*)d_ws;
  // Workspace layout (total 105,906,176 B). If the harness workspace is too
  // small, bail out cleanly (validation fails loudly instead of GPU faulting).
  if (ws_size < 105906176u) return;
  u16* xb    = (u16*)(ws);                    // 8192*2048*2 = 33554432
  u16* Wqkv  = (u16*)(ws + 33554432);         // 3072*2048*2 = 12582912
  u16* Wob   = (u16*)(ws + 46137344);         // 2048*2048*2 =  8388608
  u16* QKV   = (u16*)(ws + 54525952);         // 8192*3072*2 = 50331648
  float* cs  = (float*)(ws + 104857600);      // 131072*4    =   524288
  float* sn  = (float*)(ws + 105381888);      // total end 105906176 B

  // bf16 casts (weights packed: Wq rows 0..2047 | Wk rows 2048..2559 | Wv rows 2560..3071)
  k_cast<<<8192, 256, 0, stream>>>(x, xb, 16777216 / 8);
  k_cast<<<2048, 256, 0, stream>>>(Wq, Wqkv, 4194304 / 8);
  k_cast<<<512, 256, 0, stream>>>(Wk, Wqkv + 2048 * 2048, 1048576 / 8);
  k_cast<<<512, 256, 0, stream>>>(Wv, Wqkv + 2560 * 2048, 1048576 / 8);
  k_cast<<<2048, 256, 0, stream>>>(Wo, Wob, 4194304 / 8);
  k_rope_table<<<512, 256, 0, stream>>>(cs, sn);
  // fused QKV projection: [Q|K|V] = xb @ Wqkv^T
  k_gemm_bt<0><<<dim3(64, 24), 256, 0, stream>>>(xb, 2048, Wqkv, 2048, QKV, QW, 2048);
  // RoPE in place on Q and K regions
  k_rope_apply<<<40960, 256, 0, stream>>>(QKV, cs, sn);
  // flash attention; Z overwrites Q region of QKV
  k_attn<<<dim3(32, 16, 4), 256, 0, stream>>>(QKV);
  // out = Z @ Wo^T (fp32 out)
  k_gemm_bt<1><<<dim3(64, 16), 256, 0, stream>>>(QKV, QW, Wob, 2048, d_out, 2048, 2048);
}

// Round 5
// 554.190 us; speedup vs baseline: 1.1218x; 1.1218x over previous
//
#include <hip/hip_runtime.h>
#include <hip/hip_bf16.h>
#include <math.h>

typedef unsigned short u16;
typedef unsigned int u32;
typedef __attribute__((ext_vector_type(8))) short short8;
typedef __attribute__((ext_vector_type(8))) u16 ushort8;
typedef __attribute__((ext_vector_type(4))) float f32x4;

#define N_B 4
#define L_S 2048
#define E_D 2048
#define NH 16
#define HD 128
#define WIN 1024
#define QW 3072  // QKV buffer row width: 2048 q | 512 k | 512 v
#define LOG2E 1.4426950408889634f

static __device__ __forceinline__ u16 f32_bf16(float f) {
  u32 u = __builtin_bit_cast(u32, f);
  u = (u + 0x7fffu + ((u >> 16) & 1u)) >> 16;  // RNE
  return (u16)u;
}
static __device__ __forceinline__ float bf16_f32(u16 h) {
  u32 u = ((u32)h) << 16;
  return __builtin_bit_cast(float, u);
}
static __device__ __forceinline__ void gload_lds16(const void* g, void* l) {
  __builtin_amdgcn_global_load_lds((__attribute__((address_space(1))) void*)g,
                                   (__attribute__((address_space(3))) void*)l, 16, 0, 0);
}

// ---------------- fp32 -> bf16 cast (n multiple of 8) ----------------
__global__ void k_cast(const float* __restrict__ src, u16* __restrict__ dst, int n8) {
  int i = blockIdx.x * blockDim.x + threadIdx.x;
  if (i >= n8) return;
  const float4* s = (const float4*)src + (size_t)i * 2;
  float4 a = s[0], b = s[1];
  ushort8 v;
  v[0] = f32_bf16(a.x); v[1] = f32_bf16(a.y); v[2] = f32_bf16(a.z); v[3] = f32_bf16(a.w);
  v[4] = f32_bf16(b.x); v[5] = f32_bf16(b.y); v[6] = f32_bf16(b.z); v[7] = f32_bf16(b.w);
  *((ushort8*)dst + i) = v;
}

// ---------------- RoPE cos/sin table: [L][64] ----------------
__global__ void k_rope_table(float* __restrict__ cs, float* __restrict__ sn) {
  int idx = blockIdx.x * blockDim.x + threadIdx.x;  // 2048*64
  int l = idx >> 6, f = idx & 63;
  float freq = exp2f(-(float)f * (13.287712379549449f / 64.0f));  // 10000^(-2f/128)
  float ang = (float)l * freq;
  cs[idx] = cosf(ang);
  sn[idx] = sinf(ang);
}

// ---------------- interleaved RoPE applied in place to Q and K of QKV ----------------
__global__ void k_rope_apply(u16* __restrict__ QKV, const float* __restrict__ cs,
                             const float* __restrict__ sn) {
  int idx = blockIdx.x * blockDim.x + threadIdx.x;  // 8192*20*64 exactly
  int f = idx & 63;
  int rest = idx >> 6;
  int hh = rest % 20;          // 0..15 q heads, 16..19 kv heads
  int row = rest / 20;         // 0..8191 (= n*L + l)
  int l = row & (L_S - 1);
  int col = (hh < NH) ? (hh * HD + 2 * f) : (E_D + (hh - NH) * HD + 2 * f);
  u32* p = (u32*)(QKV + (size_t)row * QW + col);
  u32 v = *p;
  float xr = bf16_f32((u16)(v & 0xffffu));
  float xi = bf16_f32((u16)(v >> 16));
  float c = cs[l * 64 + f], s = sn[l * 64 + f];
  float orr = xr * c - xi * s;
  float oii = xr * s + xi * c;
  *p = (u32)f32_bf16(orr) | ((u32)f32_bf16(oii) << 16);
}

// ---------------- C = A @ B^T, bf16 in, bf16 or f32 out ----------------
// A: MxK row-major (lda), B: NxK row-major (ldb). 128x128 tile, BK=64, 4 waves.
template <int OUT_F32>
__global__ __launch_bounds__(256) void k_gemm_bt(
    const u16* __restrict__ A, int lda,
    const u16* __restrict__ B, int ldb,
    void* __restrict__ Cp, int ldc, int K) {
  __shared__ __align__(16) u16 As[128 * 64];
  __shared__ __align__(16) u16 Bs[128 * 64];
  const int tid = threadIdx.x;
  const int lane = tid & 63, w = tid >> 6;
  const int lr = lane & 15, lg = lane >> 4;
  const int m0 = blockIdx.x * 128, n0 = blockIdx.y * 128;
  const int wm = (w >> 1) * 64, wn = (w & 1) * 64;
  const int srow = tid >> 3, scol = (tid & 7) * 8;  // staging: 16B per lane
  const f32x4 z4 = {0.f, 0.f, 0.f, 0.f};
  f32x4 acc[4][4];
#pragma unroll
  for (int i = 0; i < 4; ++i)
#pragma unroll
    for (int j = 0; j < 4; ++j) acc[i][j] = z4;
  for (int kt = 0; kt < K; kt += 64) {
#pragma unroll
    for (int rr = 0; rr < 4; ++rr) {
      gload_lds16(A + (size_t)(m0 + rr * 32 + srow) * lda + kt + scol,
                  (char*)As + rr * 4096 + w * 1024);
      gload_lds16(B + (size_t)(n0 + rr * 32 + srow) * ldb + kt + scol,
                  (char*)Bs + rr * 4096 + w * 1024);
    }
    __syncthreads();
#pragma unroll
    for (int kk = 0; kk < 64; kk += 32) {
      short8 af[4], bfr[4];
#pragma unroll
      for (int mi = 0; mi < 4; ++mi)
        af[mi] = *(const short8*)(As + (wm + mi * 16 + lr) * 64 + kk + lg * 8);
#pragma unroll
      for (int ni = 0; ni < 4; ++ni)
        bfr[ni] = *(const short8*)(Bs + (wn + ni * 16 + lr) * 64 + kk + lg * 8);
#pragma unroll
      for (int mi = 0; mi < 4; ++mi)
#pragma unroll
        for (int ni = 0; ni < 4; ++ni)
          acc[mi][ni] =
              __builtin_amdgcn_mfma_f32_16x16x32_bf16(af[mi], bfr[ni], acc[mi][ni], 0, 0, 0);
    }
    __syncthreads();
  }
#pragma unroll
  for (int mi = 0; mi < 4; ++mi)
#pragma unroll
    for (int ni = 0; ni < 4; ++ni)
#pragma unroll
      for (int j = 0; j < 4; ++j) {
        size_t r = (size_t)(m0 + wm + mi * 16 + lg * 4 + j);
        int c = n0 + wn + ni * 16 + lr;
        if (OUT_F32)
          ((float*)Cp)[r * ldc + c] = acc[mi][ni][j];
        else
          ((u16*)Cp)[r * ldc + c] = f32_bf16(acc[mi][ni][j]);
      }
}

// ---------------- sliding-window flash attention ----------------
// Grid (L/64, H, N). 4 waves; wave w owns q-rows [qb*64+w*16, +16). KV tile = 64.
// All LDS tiles XOR-swizzled with byte ^= ((row&7)<<4); K is staged via
// global_load_lds with PRE-SWIZZLED global source (linear LDS dest, rule #21).
// Writes Z into the Q region of QKV (Q is register-resident first).
__global__ __launch_bounds__(256) void k_attn(u16* __restrict__ QKV) {
  const int qb = blockIdx.x, h = blockIdx.y, b = blockIdx.z;
  const int tid = threadIdx.x;
  const int lane = tid & 63, w = tid >> 6;
  const int lr = lane & 15, lg = lane >> 4;
  const int kh = h >> 2;
  const int qs = qb * 64 + w * 16;
  __shared__ __align__(16) u16 Klds[64 * 128];   // [kv][d], 256B rows, swizzled
  __shared__ __align__(16) u16 Vt[128 * 64];     // [d][kv], 128B rows, swizzled
  __shared__ __align__(16) u16 Plds[4][16 * 64]; // per-wave P, 128B rows, swizzled
  char* Kb = (char*)Klds;
  char* Vb = (char*)Vt;
  char* Pb = (char*)(&Plds[w][0]);
  const int swz = (lr & 7) << 4;                 // read swizzle (row = *16 + lr)
  const float scale = 0.08838834764831845f;      // 1/sqrt(128)
  const size_t bL = (size_t)b * L_S;
  const size_t rowQ = (bL + qs + lr) * QW + h * HD;
  short8 qf[4];
#pragma unroll
  for (int c = 0; c < 4; ++c) qf[c] = *(const short8*)(QKV + rowQ + c * 32 + lg * 8);
  const f32x4 z4 = {0.f, 0.f, 0.f, 0.f};
  f32x4 o[8];
#pragma unroll
  for (int dt = 0; dt < 8; ++dt) o[dt] = z4;
  float mrow[4], lrow[4];
#pragma unroll
  for (int j = 0; j < 4; ++j) { mrow[j] = -3e38f; lrow[j] = 0.f; }
  int t0 = qb * 64 - (WIN - 1);
  if (t0 < 0) t0 = 0;
  t0 >>= 6;
  const int t1 = qb;  // == (qb*64+63)>>6
  const int sKrow = tid >> 4, sKcolb = (tid & 15) * 16;
  for (int t = t0; t <= t1; ++t) {
    const int kv0 = t * 64;
    // --- stage K: linear LDS dest, pre-swizzled global source column ---
#pragma unroll
    for (int rr = 0; rr < 4; ++rr) {
      int row = rr * 16 + sKrow;                       // 0..63
      int colb = sKcolb ^ ((row & 7) << 4);            // inverse-swizzled source
      gload_lds16(QKV + (bL + kv0 + row) * QW + E_D + kh * HD + (colb >> 1),
                  Kb + rr * 4096 + w * 1024 + (lane << 4));
    }
    // --- stage V transposed (reg -> swizzled scalar ds_write) ---
#pragma unroll
    for (int rr = 0; rr < 4; ++rr) {
      int cc = rr * 256 + tid;
      int kvr = cc & 63, db = (cc >> 6) * 8;           // db multiple of 8
      short8 vv =
          *(const short8*)(QKV + (bL + kv0 + kvr) * QW + E_D + 512 + kh * HD + db);
#pragma unroll
      for (int e = 0; e < 8; ++e)
        *(u16*)(Vb + ((((db + e) * 128) + kvr * 2) ^ (e << 4))) = (u16)vv[e];
    }
    __syncthreads();
    // --- S = Q K^T: 4 col-tiles of 16 ---
    f32x4 s[4];
#pragma unroll
    for (int tile = 0; tile < 4; ++tile) s[tile] = z4;
#pragma unroll
    for (int tile = 0; tile < 4; ++tile)
#pragma unroll
      for (int c = 0; c < 4; ++c) {
        short8 kf = *(const short8*)(Kb + (((tile * 16 + lr) * 256 + c * 64 + lg * 16) ^ swz));
        s[tile] = __builtin_amdgcn_mfma_f32_16x16x32_bf16(qf[c], kf, s[tile], 0, 0, 0);
      }
    // --- online softmax (rows = lg*4+j; cols = kv0 + tile*16 + lr) ---
    float p[4][4], pmax[4];
#pragma unroll
    for (int j = 0; j < 4; ++j) {
      int gr = qs + lg * 4 + j;
      float mx = -3e38f;
#pragma unroll
      for (int tile = 0; tile < 4; ++tile) {
        int g = kv0 + tile * 16 + lr;
        bool a = (g <= gr) && (g > gr - WIN);
        float v = a ? s[tile][j] * scale : -3e38f;
        p[tile][j] = v;
        mx = fmaxf(mx, v);
      }
      mx = fmaxf(mx, __shfl_xor(mx, 1));
      mx = fmaxf(mx, __shfl_xor(mx, 2));
      mx = fmaxf(mx, __shfl_xor(mx, 4));
      mx = fmaxf(mx, __shfl_xor(mx, 8));
      pmax[j] = mx;
    }
    // defer-max (T13): rescale only when some row's max grew by > 8
    bool needr = (pmax[0] > mrow[0] + 8.f) || (pmax[1] > mrow[1] + 8.f) ||
                 (pmax[2] > mrow[2] + 8.f) || (pmax[3] > mrow[3] + 8.f);
    if (__ballot(needr)) {
      float al[4];
#pragma unroll
      for (int j = 0; j < 4; ++j) {
        float mn = fmaxf(mrow[j], pmax[j]);
        al[j] = exp2f((mrow[j] - mn) * LOG2E);
        mrow[j] = mn;
        lrow[j] *= al[j];
      }
#pragma unroll
      for (int dt = 0; dt < 8; ++dt) {
        o[dt][0] *= al[0]; o[dt][1] *= al[1]; o[dt][2] *= al[2]; o[dt][3] *= al[3];
      }
    }
#pragma unroll
    for (int j = 0; j < 4; ++j) {
      float rs = 0.f;
#pragma unroll
      for (int tile = 0; tile < 4; ++tile) {
        float pe = (p[tile][j] > -1e37f) ? exp2f((p[tile][j] - mrow[j]) * LOG2E) : 0.f;
        p[tile][j] = pe;
        rs += pe;
      }
      rs += __shfl_xor(rs, 1);
      rs += __shfl_xor(rs, 2);
      rs += __shfl_xor(rs, 4);
      rs += __shfl_xor(rs, 8);
      lrow[j] += rs;
      int R = lg * 4 + j;
      int rswz = (R & 7) << 4;
#pragma unroll
      for (int tile = 0; tile < 4; ++tile)
        *(u16*)(Pb + ((R * 128 + (tile * 16 + lr) * 2) ^ rswz)) = f32_bf16(p[tile][j]);
    }
    __syncthreads();
    // --- O += P V ---
    short8 pf0 = *(const short8*)(Pb + ((lr * 128 + 0 + lg * 16) ^ swz));
    short8 pf1 = *(const short8*)(Pb + ((lr * 128 + 64 + lg * 16) ^ swz));
#pragma unroll
    for (int dt = 0; dt < 8; ++dt) {
      short8 vf0 = *(const short8*)(Vb + (((dt * 16 + lr) * 128 + 0 + lg * 16) ^ swz));
      short8 vf1 = *(const short8*)(Vb + (((dt * 16 + lr) * 128 + 64 + lg * 16) ^ swz));
      o[dt] = __builtin_amdgcn_mfma_f32_16x16x32_bf16(pf0, vf0, o[dt], 0, 0, 0);
      o[dt] = __builtin_amdgcn_mfma_f32_16x16x32_bf16(pf1, vf1, o[dt], 0, 0, 0);
    }
    __syncthreads();
  }
  float inv[4];
#pragma unroll
  for (int j = 0; j < 4; ++j) inv[j] = 1.0f / lrow[j];
#pragma unroll
  for (int dt = 0; dt < 8; ++dt)
#pragma unroll
    for (int j = 0; j < 4; ++j) {
      size_t addr = (bL + qs + lg * 4 + j) * QW + h * HD + dt * 16 + lr;
      QKV[addr] = f32_bf16(o[dt][j] * inv[j]);
    }
}

extern "C" void kernel_launch(void* const* d_in, const int* in_sizes, int n_in,
                              void* d_out, int out_size, void* d_ws, size_t ws_size,
                              hipStream_t stream) {
  const float* x  = (const float*)d_in[0];
  const float* Wq = (const float*)d_in[1];
  const float* Wk = (const float*)d_in[2];
  const float* Wv = (const float*)d_in[3];
  const float* Wo = (const float*)d_in[4];
  char* ws = (char*)d_ws;
  // Workspace layout (total 105,906,176 B). If the harness workspace is too
  // small, bail out cleanly (validation fails loudly instead of GPU faulting).
  if (ws_size < 105906176u) return;
  u16* xb    = (u16*)(ws);                    // 8192*2048*2 = 33554432
  u16* Wqkv  = (u16*)(ws + 33554432);         // 3072*2048*2 = 12582912
  u16* Wob   = (u16*)(ws + 46137344);         // 2048*2048*2 =  8388608
  u16* QKV   = (u16*)(ws + 54525952);         // 8192*3072*2 = 50331648
  float* cs  = (float*)(ws + 104857600);      // 131072*4    =   524288
  float* sn  = (float*)(ws + 105381888);      // total end 105906176 B

  // bf16 casts (weights packed: Wq rows 0..2047 | Wk rows 2048..2559 | Wv rows 2560..3071)
  k_cast<<<8192, 256, 0, stream>>>(x, xb, 16777216 / 8);
  k_cast<<<2048, 256, 0, stream>>>(Wq, Wqkv, 4194304 / 8);
  k_cast<<<512, 256, 0, stream>>>(Wk, Wqkv + 2048 * 2048, 1048576 / 8);
  k_cast<<<512, 256, 0, stream>>>(Wv, Wqkv + 2560 * 2048, 1048576 / 8);
  k_cast<<<2048, 256, 0, stream>>>(Wo, Wob, 4194304 / 8);
  k_rope_table<<<512, 256, 0, stream>>>(cs, sn);
  // fused QKV projection: [Q|K|V] = xb @ Wqkv^T
  k_gemm_bt<0><<<dim3(64, 24), 256, 0, stream>>>(xb, 2048, Wqkv, 2048, QKV, QW, 2048);
  // RoPE in place on Q and K regions
  k_rope_apply<<<40960, 256, 0, stream>>>(QKV, cs, sn);
  // flash attention; Z overwrites Q region of QKV
  k_attn<<<dim3(32, 16, 4), 256, 0, stream>>>(QKV);
  // out = Z @ Wo^T (fp32 out)
  k_gemm_bt<1><<<dim3(64, 16), 256, 0, stream>>>(QKV, QW, Wob, 2048, d_out, 2048, 2048);
}

// Round 6
// 532.089 us; speedup vs baseline: 1.1684x; 1.0415x over previous
//
#include <hip/hip_runtime.h>
#include <hip/hip_bf16.h>
#include <math.h>

typedef unsigned short u16;
typedef unsigned int u32;
typedef __attribute__((ext_vector_type(8))) short short8;
typedef __attribute__((ext_vector_type(8))) u16 ushort8;
typedef __attribute__((ext_vector_type(4))) float f32x4;

#define N_B 4
#define L_S 2048
#define E_D 2048
#define NH 16
#define HD 128
#define WIN 1024
#define QW 3072  // QKV buffer row width: 2048 q | 512 k | 512 v
#define LOG2E 1.4426950408889634f

static __device__ __forceinline__ u16 f32_bf16(float f) {
  u32 u = __builtin_bit_cast(u32, f);
  u = (u + 0x7fffu + ((u >> 16) & 1u)) >> 16;  // RNE
  return (u16)u;
}
static __device__ __forceinline__ float bf16_f32(u16 h) {
  u32 u = ((u32)h) << 16;
  return __builtin_bit_cast(float, u);
}
static __device__ __forceinline__ void gload_lds16(const void* g, void* l) {
  __builtin_amdgcn_global_load_lds((__attribute__((address_space(1))) void*)g,
                                   (__attribute__((address_space(3))) void*)l, 16, 0, 0);
}

// ---------------- fp32 -> bf16 cast (n multiple of 8) ----------------
__global__ void k_cast(const float* __restrict__ src, u16* __restrict__ dst, int n8) {
  int i = blockIdx.x * blockDim.x + threadIdx.x;
  if (i >= n8) return;
  const float4* s = (const float4*)src + (size_t)i * 2;
  float4 a = s[0], b = s[1];
  ushort8 v;
  v[0] = f32_bf16(a.x); v[1] = f32_bf16(a.y); v[2] = f32_bf16(a.z); v[3] = f32_bf16(a.w);
  v[4] = f32_bf16(b.x); v[5] = f32_bf16(b.y); v[6] = f32_bf16(b.z); v[7] = f32_bf16(b.w);
  *((ushort8*)dst + i) = v;
}

// ---------------- RoPE cos/sin table: [L][64] ----------------
__global__ void k_rope_table(float* __restrict__ cs, float* __restrict__ sn) {
  int idx = blockIdx.x * blockDim.x + threadIdx.x;  // 2048*64
  int l = idx >> 6, f = idx & 63;
  float freq = exp2f(-(float)f * (13.287712379549449f / 64.0f));  // 10000^(-2f/128)
  float ang = (float)l * freq;
  cs[idx] = cosf(ang);
  sn[idx] = sinf(ang);
}

// ---------------- interleaved RoPE applied in place to Q and K of QKV ----------------
__global__ void k_rope_apply(u16* __restrict__ QKV, const float* __restrict__ cs,
                             const float* __restrict__ sn) {
  int idx = blockIdx.x * blockDim.x + threadIdx.x;  // 8192*20*64 exactly
  int f = idx & 63;
  int rest = idx >> 6;
  int hh = rest % 20;          // 0..15 q heads, 16..19 kv heads
  int row = rest / 20;         // 0..8191 (= n*L + l)
  int l = row & (L_S - 1);
  int col = (hh < NH) ? (hh * HD + 2 * f) : (E_D + (hh - NH) * HD + 2 * f);
  u32* p = (u32*)(QKV + (size_t)row * QW + col);
  u32 v = *p;
  float xr = bf16_f32((u16)(v & 0xffffu));
  float xi = bf16_f32((u16)(v >> 16));
  float c = cs[l * 64 + f], s = sn[l * 64 + f];
  float orr = xr * c - xi * s;
  float oii = xr * s + xi * c;
  *p = (u32)f32_bf16(orr) | ((u32)f32_bf16(oii) << 16);
}

// ---------------- C = A @ B^T, bf16 in, bf16 or f32 out ----------------
// A: MxK row-major (lda), B: NxK row-major (ldb). 128x128 tile, BK=64, 4 waves.
template <int OUT_F32>
__global__ __launch_bounds__(256) void k_gemm_bt(
    const u16* __restrict__ A, int lda,
    const u16* __restrict__ B, int ldb,
    void* __restrict__ Cp, int ldc, int K) {
  __shared__ __align__(16) u16 As[128 * 64];
  __shared__ __align__(16) u16 Bs[128 * 64];
  const int tid = threadIdx.x;
  const int lane = tid & 63, w = tid >> 6;
  const int lr = lane & 15, lg = lane >> 4;
  const int m0 = blockIdx.x * 128, n0 = blockIdx.y * 128;
  const int wm = (w >> 1) * 64, wn = (w & 1) * 64;
  const int srow = tid >> 3, scol = (tid & 7) * 8;  // staging: 16B per lane
  const f32x4 z4 = {0.f, 0.f, 0.f, 0.f};
  f32x4 acc[4][4];
#pragma unroll
  for (int i = 0; i < 4; ++i)
#pragma unroll
    for (int j = 0; j < 4; ++j) acc[i][j] = z4;
  for (int kt = 0; kt < K; kt += 64) {
#pragma unroll
    for (int rr = 0; rr < 4; ++rr) {
      gload_lds16(A + (size_t)(m0 + rr * 32 + srow) * lda + kt + scol,
                  (char*)As + rr * 4096 + w * 1024);
      gload_lds16(B + (size_t)(n0 + rr * 32 + srow) * ldb + kt + scol,
                  (char*)Bs + rr * 4096 + w * 1024);
    }
    __syncthreads();
#pragma unroll
    for (int kk = 0; kk < 64; kk += 32) {
      short8 af[4], bfr[4];
#pragma unroll
      for (int mi = 0; mi < 4; ++mi)
        af[mi] = *(const short8*)(As + (wm + mi * 16 + lr) * 64 + kk + lg * 8);
#pragma unroll
      for (int ni = 0; ni < 4; ++ni)
        bfr[ni] = *(const short8*)(Bs + (wn + ni * 16 + lr) * 64 + kk + lg * 8);
#pragma unroll
      for (int mi = 0; mi < 4; ++mi)
#pragma unroll
        for (int ni = 0; ni < 4; ++ni)
          acc[mi][ni] =
              __builtin_amdgcn_mfma_f32_16x16x32_bf16(af[mi], bfr[ni], acc[mi][ni], 0, 0, 0);
    }
    __syncthreads();
  }
#pragma unroll
  for (int mi = 0; mi < 4; ++mi)
#pragma unroll
    for (int ni = 0; ni < 4; ++ni)
#pragma unroll
      for (int j = 0; j < 4; ++j) {
        size_t r = (size_t)(m0 + wm + mi * 16 + lg * 4 + j);
        int c = n0 + wn + ni * 16 + lr;
        if (OUT_F32)
          ((float*)Cp)[r * ldc + c] = acc[mi][ni][j];
        else
          ((u16*)Cp)[r * ldc + c] = f32_bf16(acc[mi][ni][j]);
      }
}

// ---------------- sliding-window flash attention (pipelined) ----------------
// Grid (L/64, H, N). 4 waves; wave w owns q-rows [qb*64+w*16, +16). KV tile = 64.
// Double-buffered K (global_load_lds, pre-swizzled source) and V (reg-staged,
// swizzled ds_write). K(t+1)/V(t+1) issued at loop top, drained at barrier1 ->
// memory latency hidden under QK^T+softmax. Writes Z into the Q region of QKV.
__global__ __launch_bounds__(256) void k_attn(u16* __restrict__ QKV) {
  const int qb = blockIdx.x, h = blockIdx.y, b = blockIdx.z;
  const int tid = threadIdx.x;
  const int lane = tid & 63, w = tid >> 6;
  const int lr = lane & 15, lg = lane >> 4;
  const int kh = h >> 2;
  const int qs = qb * 64 + w * 16;
  __shared__ __align__(16) u16 Klds[2][64 * 128];  // [kv][d], swizzled, 2 buffers
  __shared__ __align__(16) u16 Vt[2][128 * 64];    // [d][kv], swizzled, 2 buffers
  __shared__ __align__(16) u16 Plds[4][16 * 64];   // per-wave P, swizzled
  char* Pb = (char*)(&Plds[w][0]);
  const int swz = (lr & 7) << 4;                   // read swizzle (row = *16 + lr)
  const float scale = 0.08838834764831845f;        // 1/sqrt(128)
  const size_t bL = (size_t)b * L_S;
  const size_t rowQ = (bL + qs + lr) * QW + h * HD;
  short8 qf[4];
#pragma unroll
  for (int c = 0; c < 4; ++c) qf[c] = *(const short8*)(QKV + rowQ + c * 32 + lg * 8);
  const f32x4 z4 = {0.f, 0.f, 0.f, 0.f};
  f32x4 o[8];
#pragma unroll
  for (int dt = 0; dt < 8; ++dt) o[dt] = z4;
  float mrow[4], lrow[4];
#pragma unroll
  for (int j = 0; j < 4; ++j) { mrow[j] = -3e38f; lrow[j] = 0.f; }
  int t0 = qb * 64 - (WIN - 1);
  if (t0 < 0) t0 = 0;
  t0 >>= 6;
  const int t1 = qb;  // == (qb*64+63)>>6
  const int sKrow = tid >> 4, sKcolb = (tid & 15) * 16;
  short8 vreg[4];

  // --- staging helpers ---
  auto ISSUE_K = [&](int t, int buf) {
    char* Kb = (char*)Klds + buf * 16384;
#pragma unroll
    for (int rr = 0; rr < 4; ++rr) {
      int row = rr * 16 + sKrow;                   // 0..63
      int colb = sKcolb ^ ((row & 7) << 4);        // inverse-swizzled source col
      gload_lds16(QKV + (bL + t * 64 + row) * QW + E_D + kh * HD + (colb >> 1),
                  Kb + rr * 4096 + w * 1024 + (lane << 4));
    }
  };
  auto LOAD_V = [&](int t) {
#pragma unroll
    for (int rr = 0; rr < 4; ++rr)
      vreg[rr] = *(const short8*)(QKV + (bL + t * 64 + lane) * QW + E_D + 512 + kh * HD +
                                  (rr * 4 + w) * 8);
  };
  auto WRITE_V = [&](int buf) {
    char* Vb = (char*)Vt + buf * 16384;
#pragma unroll
    for (int rr = 0; rr < 4; ++rr) {
      int db = (rr * 4 + w) * 8;                   // multiple of 8 -> row&7 == e
#pragma unroll
      for (int e = 0; e < 8; ++e)
        *(u16*)(Vb + ((((db + e) * 128) + lane * 2) ^ (e << 4))) = (u16)vreg[rr][e];
    }
  };

  // --- prologue: stage tile t0 ---
  LOAD_V(t0);
  ISSUE_K(t0, 0);
  __syncthreads();          // drains K gloads + V reg loads
  WRITE_V(0);               // visible to all waves after barrier1 of iter t0
  int c = 0;

  for (int t = t0; t <= t1; ++t) {
    const int kv0 = t * 64;
    const int tn = (t < t1) ? t + 1 : t1;
    // prefetch next tile: K -> Klds[c^1] (async), V -> regs. Both fly until barrier1.
    ISSUE_K(tn, c ^ 1);
    LOAD_V(tn);
    // --- S = Q K^T from Klds[c]: 4 col-tiles of 16 ---
    char* Kb = (char*)Klds + c * 16384;
    f32x4 s[4];
#pragma unroll
    for (int tile = 0; tile < 4; ++tile) s[tile] = z4;
#pragma unroll
    for (int tile = 0; tile < 4; ++tile)
#pragma unroll
      for (int cc = 0; cc < 4; ++cc) {
        short8 kf = *(const short8*)(Kb + (((tile * 16 + lr) * 256 + cc * 64 + lg * 16) ^ swz));
        s[tile] = __builtin_amdgcn_mfma_f32_16x16x32_bf16(qf[cc], kf, s[tile], 0, 0, 0);
      }
    // --- online softmax (rows = lg*4+j; cols = kv0 + tile*16 + lr) ---
    float p[4][4], pmax[4];
#pragma unroll
    for (int j = 0; j < 4; ++j) {
      int gr = qs + lg * 4 + j;
      float mx = -3e38f;
#pragma unroll
      for (int tile = 0; tile < 4; ++tile) {
        int g = kv0 + tile * 16 + lr;
        bool a = (g <= gr) && (g > gr - WIN);
        float v = a ? s[tile][j] * scale : -3e38f;
        p[tile][j] = v;
        mx = fmaxf(mx, v);
      }
      mx = fmaxf(mx, __shfl_xor(mx, 1));
      mx = fmaxf(mx, __shfl_xor(mx, 2));
      mx = fmaxf(mx, __shfl_xor(mx, 4));
      mx = fmaxf(mx, __shfl_xor(mx, 8));
      pmax[j] = mx;
    }
    // defer-max (T13): rescale only when some row's max grew by > 8
    bool needr = (pmax[0] > mrow[0] + 8.f) || (pmax[1] > mrow[1] + 8.f) ||
                 (pmax[2] > mrow[2] + 8.f) || (pmax[3] > mrow[3] + 8.f);
    if (__ballot(needr)) {
      float al[4];
#pragma unroll
      for (int j = 0; j < 4; ++j) {
        float mn = fmaxf(mrow[j], pmax[j]);
        al[j] = exp2f((mrow[j] - mn) * LOG2E);
        mrow[j] = mn;
        lrow[j] *= al[j];
      }
#pragma unroll
      for (int dt = 0; dt < 8; ++dt) {
        o[dt][0] *= al[0]; o[dt][1] *= al[1]; o[dt][2] *= al[2]; o[dt][3] *= al[3];
      }
    }
#pragma unroll
    for (int j = 0; j < 4; ++j) {
      float rs = 0.f;
#pragma unroll
      for (int tile = 0; tile < 4; ++tile) {
        float pe = (p[tile][j] > -1e37f) ? exp2f((p[tile][j] - mrow[j]) * LOG2E) : 0.f;
        p[tile][j] = pe;
        rs += pe;
      }
      rs += __shfl_xor(rs, 1);
      rs += __shfl_xor(rs, 2);
      rs += __shfl_xor(rs, 4);
      rs += __shfl_xor(rs, 8);
      lrow[j] += rs;
      int R = lg * 4 + j;
      int rswz = (R & 7) << 4;
#pragma unroll
      for (int tile = 0; tile < 4; ++tile)
        *(u16*)(Pb + ((R * 128 + (tile * 16 + lr) * 2) ^ rswz)) = f32_bf16(p[tile][j]);
    }
    __syncthreads();  // barrier1: drains K(tn)+V(tn) loads; P + Vt[c] visible
    // stage V(tn) into the spare buffer (PV below reads Vt[c], no overlap)
    WRITE_V(c ^ 1);
    // --- O += P V from Vt[c] ---
    char* Vb = (char*)Vt + c * 16384;
    short8 pf0 = *(const short8*)(Pb + ((lr * 128 + 0 + lg * 16) ^ swz));
    short8 pf1 = *(const short8*)(Pb + ((lr * 128 + 64 + lg * 16) ^ swz));
    __builtin_amdgcn_s_setprio(1);
#pragma unroll
    for (int dt = 0; dt < 8; ++dt) {
      short8 vf0 = *(const short8*)(Vb + (((dt * 16 + lr) * 128 + 0 + lg * 16) ^ swz));
      short8 vf1 = *(const short8*)(Vb + (((dt * 16 + lr) * 128 + 64 + lg * 16) ^ swz));
      o[dt] = __builtin_amdgcn_mfma_f32_16x16x32_bf16(pf0, vf0, o[dt], 0, 0, 0);
      o[dt] = __builtin_amdgcn_mfma_f32_16x16x32_bf16(pf1, vf1, o[dt], 0, 0, 0);
    }
    __builtin_amdgcn_s_setprio(0);
    __syncthreads();  // barrier2: protects Plds/Vt[c] reuse next iter (no VMEM pending)
    c ^= 1;
  }
  float inv[4];
#pragma unroll
  for (int j = 0; j < 4; ++j) inv[j] = 1.0f / lrow[j];
#pragma unroll
  for (int dt = 0; dt < 8; ++dt)
#pragma unroll
    for (int j = 0; j < 4; ++j) {
      size_t addr = (bL + qs + lg * 4 + j) * QW + h * HD + dt * 16 + lr;
      QKV[addr] = f32_bf16(o[dt][j] * inv[j]);
    }
}

extern "C" void kernel_launch(void* const* d_in, const int* in_sizes, int n_in,
                              void* d_out, int out_size, void* d_ws, size_t ws_size,
                              hipStream_t stream) {
  const float* x  = (const float*)d_in[0];
  const float* Wq = (const float*)d_in[1];
  const float* Wk = (const float*)d_in[2];
  const float* Wv = (const float*)d_in[3];
  const float* Wo = (const float*)d_in[4];
  char* ws = (char*)d_ws;
  // Workspace layout (total 105,906,176 B). If the harness workspace is too
  // small, bail out cleanly (validation fails loudly instead of GPU faulting).
  if (ws_size < 105906176u) return;
  u16* xb    = (u16*)(ws);                    // 8192*2048*2 = 33554432
  u16* Wqkv  = (u16*)(ws + 33554432);         // 3072*2048*2 = 12582912
  u16* Wob   = (u16*)(ws + 46137344);         // 2048*2048*2 =  8388608
  u16* QKV   = (u16*)(ws + 54525952);         // 8192*3072*2 = 50331648
  float* cs  = (float*)(ws + 104857600);      // 131072*4    =   524288
  float* sn  = (float*)(ws + 105381888);      // total end 105906176 B

  // bf16 casts (weights packed: Wq rows 0..2047 | Wk rows 2048..2559 | Wv rows 2560..3071)
  k_cast<<<8192, 256, 0, stream>>>(x, xb, 16777216 / 8);
  k_cast<<<2048, 256, 0, stream>>>(Wq, Wqkv, 4194304 / 8);
  k_cast<<<512, 256, 0, stream>>>(Wk, Wqkv + 2048 * 2048, 1048576 / 8);
  k_cast<<<512, 256, 0, stream>>>(Wv, Wqkv + 2560 * 2048, 1048576 / 8);
  k_cast<<<2048, 256, 0, stream>>>(Wo, Wob, 4194304 / 8);
  k_rope_table<<<512, 256, 0, stream>>>(cs, sn);
  // fused QKV projection: [Q|K|V] = xb @ Wqkv^T
  k_gemm_bt<0><<<dim3(64, 24), 256, 0, stream>>>(xb, 2048, Wqkv, 2048, QKV, QW, 2048);
  // RoPE in place on Q and K regions
  k_rope_apply<<<40960, 256, 0, stream>>>(QKV, cs, sn);
  // flash attention; Z overwrites Q region of QKV
  k_attn<<<dim3(32, 16, 4), 256, 0, stream>>>(QKV);
  // out = Z @ Wo^T (fp32 out)
  k_gemm_bt<1><<<dim3(64, 16), 256, 0, stream>>>(QKV, QW, Wob, 2048, d_out, 2048, 2048);
}